// Round 4
// baseline (154.168 us; speedup 1.0000x reference)
//
#include <hip/hip_runtime.h>
#include <cfloat>
#include <cstdint>

#define BB 8
#define CCH 64
#define HH 128
#define WW 128
#define HW (HH * WW)
#define NUM 32
#define PLANES (BB * CCH)
#define NTHREADS 256

// ---- new split-path parameters ----
#define CAPP 3072                     // per-plane candidate cap (mean ~1820)
#define KREG2 12                      // CAPP / NTHREADS
#define NCTR 2048                     // counters region (ints), only PLANES used
#define WS_NEED2 ((size_t)NCTR * 4 + (size_t)PLANES * CAPP * 8)   // ~12.6 MB
#define PREFMASK 0xFFFFFFFFFFFFC000ull
#define POSKEY   0x8000000000000000ull

// ---- monolith fallback parameters ----
#define CAND_CAP 2176
#define KREG 9

// f64 window-sum at (i,j) with zero padding, fixed summation order.
__device__ double ws_at(const float* xpl, int i, int j) {
    double h[3];
    for (int d = -1; d <= 1; ++d) {
        int r = i + d;
        double a = 0.0, b = 0.0, c = 0.0;
        if (r >= 0 && r < HH) {
            const float* row = xpl + r * WW;
            a = (j - 1 >= 0) ? (double)row[j - 1] : 0.0;
            b = (double)row[j];
            c = (j + 1 < WW) ? (double)row[j + 1] : 0.0;
        }
        h[d + 1] = a + b + c;
    }
    return h[0] + h[1] + h[2];
}

__device__ bool is_peak(const float* xpl, int i, int j) {
    double v = ws_at(xpl, i, j);
    for (int di = -1; di <= 1; ++di)
        for (int dj = -1; dj <= 1; ++dj) {
            if (di == 0 && dj == 0) continue;
            int r = i + di, c = j + dj;
            if (r < 0 || r >= HH || c < 0 || c >= WW) continue;
            if (ws_at(xpl, r, c) > v) return false;
        }
    return true;
}

__device__ __forceinline__ bool better(double av, int ai, double bv, int bi) {
    return (av > bv) || (av == bv && ai < bi);
}

// order-preserving u64 of a double, then pack (value-prefix | 0x3FFF - idx)
__device__ __forceinline__ unsigned long long pack_key(double v, int idx) {
    unsigned long long u = (unsigned long long)__double_as_longlong(v);
    unsigned long long ord = u ^ (0x8000000000000000ull | (unsigned long long)((long long)u >> 63));
    return (ord & PREFMASK) | (unsigned long long)(0x3FFF - idx);
}

// ======================= Kernel 1: pure stencil, peaks -> global pool =======================
__global__ __launch_bounds__(NTHREADS, 8) void nms_stencil(const float* __restrict__ x,
                                                           int* __restrict__ counters,
                                                           unsigned long long* __restrict__ pool) {
    const int blk = blockIdx.x;   // 2048 blocks
    const int p = blk >> 2;       // plane
    const int q = blk & 3;        // quarter
    const float* xpl = x + (size_t)p * HW;
    const int tid = threadIdx.x;
    const int lane = tid & 63;
    unsigned long long* ppool = pool + (size_t)p * CAPP;
    int* pctr = counters + p;

    __shared__ float xs[36 * 128];   // 18432 B -> 8 blocks/CU

    const int base_row = q * 32 - 2;
    for (int k = tid; k < 36 * 32; k += NTHREADS) {
        int rr = k >> 5, c4 = (k & 31) << 2;
        int gr = base_row + rr;
        float4 v = make_float4(0.f, 0.f, 0.f, 0.f);
        if (gr >= 0 && gr < HH) v = *(const float4*)(xpl + gr * WW + c4);
        *(float4*)(&xs[rr * 128 + c4]) = v;
    }
    __syncthreads();

    const int j = tid & 127;
    const int s = tid >> 7;
    const int i0 = q * 32 + s * 16;   // 16 rows per thread

    auto HS3 = [&](int r, double h[3]) {
        const float* row = &xs[(r - base_row) * 128];
        double a = (j >= 2) ? (double)row[j - 2] : 0.0;
        double b = (j >= 1) ? (double)row[j - 1] : 0.0;
        double c = (double)row[j];
        double d = (j <= 126) ? (double)row[j + 1] : 0.0;
        double e = (j <= 125) ? (double)row[j + 2] : 0.0;
        h[0] = a + b + c;
        h[1] = b + c + d;
        h[2] = c + d + e;
    };

    double hA[3], hB[3], hC[3];
    double wm[3], wc[3], wn[3];
    {
        double h0[3], h1[3];
        HS3(i0 - 2, h0);
        HS3(i0 - 1, h1);
        HS3(i0, hA);
        HS3(i0 + 1, hB);
        if (i0 - 1 >= 0) {
            wm[0] = h0[0] + h1[0] + hA[0];
            wm[1] = h0[1] + h1[1] + hA[1];
            wm[2] = h0[2] + h1[2] + hA[2];
        } else {
            wm[0] = wm[1] = wm[2] = -DBL_MAX;  // max-pool -inf pad
        }
        wc[0] = h1[0] + hA[0] + hB[0];
        wc[1] = h1[1] + hA[1] + hB[1];
        wc[2] = h1[2] + hA[2] + hB[2];
    }
    for (int i = i0; i < i0 + 16; ++i) {
        HS3(i + 2, hC);
        if (i + 1 < HH) {
            wn[0] = hA[0] + hB[0] + hC[0];
            wn[1] = hA[1] + hB[1] + hC[1];
            wn[2] = hA[2] + hB[2] + hC[2];
        } else {
            wn[0] = wn[1] = wn[2] = -DBL_MAX;
        }
        double v = wc[1];
        bool pk = (v >= wm[1]) && (v >= wn[1]);
        if (j > 0)   pk = pk && (v >= wm[0]) && (v >= wc[0]) && (v >= wn[0]);
        if (j < 127) pk = pk && (v >= wm[2]) && (v >= wc[2]) && (v >= wn[2]);

        // ballot-compacted append to global pool
        unsigned long long mask = __ballot(pk);
        if (mask) {
            int leader = __ffsll(mask) - 1;
            int nact = __popcll(mask);
            int base = 0;
            if (lane == leader) base = atomicAdd(pctr, nact);
            base = __shfl(base, leader);
            if (pk) {
                int slot = base + __popcll(mask & ((1ull << lane) - 1ull));
                if (slot < CAPP) ppool[slot] = pack_key(v, i * WW + j);
            }
        }

        wm[0] = wc[0]; wm[1] = wc[1]; wm[2] = wc[2];
        wc[0] = wn[0]; wc[1] = wn[1]; wc[2] = wn[2];
        hA[0] = hB[0]; hA[1] = hB[1]; hA[2] = hB[2];
        hB[0] = hC[0]; hB[1] = hC[1]; hB[2] = hC[2];
    }
}

// ======================= Kernel 2: per-plane top-32 on u64 keys + gather =======================
__global__ __launch_bounds__(NTHREADS) void nms_select(const float* __restrict__ x,
                                                       const int* __restrict__ counters,
                                                       const unsigned long long* __restrict__ pool,
                                                       float* __restrict__ out) {
    const int p = blockIdx.x;
    const int tid = threadIdx.x;
    const int lane = tid & 63;
    const int wid = tid >> 6;
    const float* xpl = x + (size_t)p * HW;
    const unsigned long long* pp = pool + (size_t)p * CAPP;

    __shared__ unsigned long long merge_key[4 * NUM];
    __shared__ int sel_idx[NUM];
    __shared__ int nsel_s;

    const int P = min(counters[p], CAPP);

    unsigned long long lk[KREG2];
#pragma unroll
    for (int r = 0; r < KREG2; ++r) {
        int ci = tid + (r << 8);
        lk[r] = (ci < P) ? pp[ci] : 0ull;
    }

    // per-wave top-32 (keys unique; 0 = sentinel)
    unsigned long long keep = 0ull;
    for (int round = 0; round < NUM; ++round) {
        unsigned long long b = 0ull;
#pragma unroll
        for (int r = 0; r < KREG2; ++r) b = (lk[r] > b) ? lk[r] : b;
#pragma unroll
        for (int off = 1; off < 64; off <<= 1) {
            unsigned long long o = __shfl_xor(b, off);
            b = (o > b) ? o : b;
        }
        if (lane == round) keep = b;
#pragma unroll
        for (int r = 0; r < KREG2; ++r)
            if (lk[r] == b) lk[r] = 0ull;
    }
    if (lane < NUM) merge_key[wid * NUM + lane] = keep;
    __syncthreads();

    // wave0: 128 -> 32 final merge, strictly-positive-value check
    if (wid == 0) {
        unsigned long long c0 = merge_key[lane], c1 = merge_key[64 + lane];
        int cnt = 0;
        for (int round = 0; round < NUM; ++round) {
            unsigned long long b = (c1 > c0) ? c1 : c0;
#pragma unroll
            for (int off = 1; off < 64; off <<= 1) {
                unsigned long long o = __shfl_xor(b, off);
                b = (o > b) ? o : b;
            }
            if (!((b & PREFMASK) > POSKEY)) break;  // only v>0 beats the zero pool
            if (lane == 0) sel_idx[round] = 0x3FFF - (int)(b & 0x3FFFull);
            cnt++;
            if (c0 == b) c0 = 0ull;
            if (c1 == b) c1 = 0ull;
        }
        if (lane == 0) nsel_s = cnt;
    }
    __syncthreads();
    const int S = nsel_s;
    // Degenerate fallback (<32 strictly-positive peaks) — never taken for this data.
    if (tid == 0 && S < NUM) {
        int fill = S;
        for (int idx = 0; idx < HW && fill < NUM; ++idx) {
            int ii = idx >> 7, jj = idx & 127;
            double v = ws_at(xpl, ii, jj);
            bool zp = !(is_peak(xpl, ii, jj) && v != 0.0);
            if (zp) sel_idx[fill++] = idx;
        }
    }
    __syncthreads();

    if (tid < NUM) {
        const int idx = sel_idx[tid];
        const int h = idx >> 7, w = idx & 127;
        float* o0 = out + ((size_t)p * NUM + tid) * 9;
        for (int dr = 0; dr < 3; ++dr)
            for (int dc = 0; dc < 3; ++dc) {
                int rr = h - 1 + dr, cc = w - 1 + dc;
                float v = 0.f;
                if (rr >= 0 && rr < HH && cc >= 0 && cc < WW) v = xpl[rr * WW + cc];
                o0[dr * 3 + dc] = v;
            }
        float* o1 = out + (size_t)PLANES * NUM * 9 + ((size_t)p * NUM + tid) * 4;
        int x1 = max(w - 1, 0), y1 = max(h - 1, 0);
        int x2 = min(w + 1, WW - 1), y2 = min(h + 1, HH - 1);
        o1[0] = (float)x1;
        o1[1] = (float)y1;
        o1[2] = (float)x2;
        o1[3] = (float)y2;
    }
}

// ======================= Fallback monolith (proven, R2) =======================
__global__ __launch_bounds__(NTHREADS) void nms_kernel(const float* __restrict__ x,
                                                       float* __restrict__ out) {
    const int p = blockIdx.x;
    const float* xpl = x + (size_t)p * HW;
    const int tid = threadIdx.x;
    const int lane = tid & 63;
    const int wid = tid >> 6;

    __shared__ float xs[68 * 128];
    __shared__ double cand_val[CAND_CAP];
    __shared__ int cand_idx[CAND_CAP];
    __shared__ int cand_cnt;
    __shared__ double merge_val[4 * NUM];
    __shared__ int merge_idx[4 * NUM];
    __shared__ double topk_val[NUM];
    __shared__ int topk_idx[NUM];
    __shared__ int nsel;
    __shared__ int sel_idx[NUM];

    if (tid == 0) nsel = 0;

    const int j = tid & 127;
    const int s = tid >> 7;

    for (int half = 0; half < 2; ++half) {
        const int base_row = half * 64 - 2;
        __syncthreads();
        if (tid == 0) cand_cnt = 0;
        for (int k = tid; k < 68 * 32; k += NTHREADS) {
            int rr = k >> 5, c4 = (k & 31) << 2;
            int gr = base_row + rr;
            float4 v = make_float4(0.f, 0.f, 0.f, 0.f);
            if (gr >= 0 && gr < HH) v = *(const float4*)(xpl + gr * WW + c4);
            *(float4*)(&xs[rr * 128 + c4]) = v;
        }
        __syncthreads();

        const int i0 = half * 64 + s * 32;

        auto HS3 = [&](int r, double h[3]) {
            const float* row = &xs[(r - base_row) * 128];
            double a = (j >= 2) ? (double)row[j - 2] : 0.0;
            double b = (j >= 1) ? (double)row[j - 1] : 0.0;
            double c = (double)row[j];
            double d = (j <= 126) ? (double)row[j + 1] : 0.0;
            double e = (j <= 125) ? (double)row[j + 2] : 0.0;
            h[0] = a + b + c;
            h[1] = b + c + d;
            h[2] = c + d + e;
        };

        double hA[3], hB[3], hC[3];
        double wm[3], wc[3], wn[3];
        {
            double h0[3], h1[3];
            HS3(i0 - 2, h0);
            HS3(i0 - 1, h1);
            HS3(i0, hA);
            HS3(i0 + 1, hB);
            if (i0 - 1 >= 0) {
                wm[0] = h0[0] + h1[0] + hA[0];
                wm[1] = h0[1] + h1[1] + hA[1];
                wm[2] = h0[2] + h1[2] + hA[2];
            } else {
                wm[0] = wm[1] = wm[2] = -DBL_MAX;
            }
            wc[0] = h1[0] + hA[0] + hB[0];
            wc[1] = h1[1] + hA[1] + hB[1];
            wc[2] = h1[2] + hA[2] + hB[2];
        }
        for (int i = i0; i < i0 + 32; ++i) {
            HS3(i + 2, hC);
            if (i + 1 < HH) {
                wn[0] = hA[0] + hB[0] + hC[0];
                wn[1] = hA[1] + hB[1] + hC[1];
                wn[2] = hA[2] + hB[2] + hC[2];
            } else {
                wn[0] = wn[1] = wn[2] = -DBL_MAX;
            }
            double v = wc[1];
            bool pk = (v >= wm[1]) && (v >= wn[1]);
            if (j > 0)   pk = pk && (v >= wm[0]) && (v >= wc[0]) && (v >= wn[0]);
            if (j < 127) pk = pk && (v >= wm[2]) && (v >= wc[2]) && (v >= wn[2]);
            if (pk) {
                int pos = atomicAdd(&cand_cnt, 1);
                if (pos < CAND_CAP) { cand_val[pos] = v; cand_idx[pos] = i * WW + j; }
            }
            wm[0] = wc[0]; wm[1] = wc[1]; wm[2] = wc[2];
            wc[0] = wn[0]; wc[1] = wn[1]; wc[2] = wn[2];
            hA[0] = hB[0]; hA[1] = hB[1]; hA[2] = hB[2];
            hB[0] = hC[0]; hB[1] = hC[1]; hB[2] = hC[2];
        }

        if (tid < nsel) {
            int pos = atomicAdd(&cand_cnt, 1);
            if (pos < CAND_CAP) { cand_val[pos] = topk_val[tid]; cand_idx[pos] = topk_idx[tid]; }
        }
        __syncthreads();
        const int P = min(cand_cnt, CAND_CAP);

        double lv[KREG];
        int li[KREG];
#pragma unroll
        for (int r = 0; r < KREG; ++r) {
            int ci = tid + (r << 8);
            if (ci < P) { lv[r] = cand_val[ci]; li[r] = cand_idx[ci]; }
            else        { lv[r] = -DBL_MAX;     li[r] = 0x7FFFFFFF; }
        }
        double keep_v = -DBL_MAX;
        int keep_i = 0x7FFFFFFF;
        for (int round = 0; round < NUM; ++round) {
            double bv = -DBL_MAX;
            int bi_ = 0x7FFFFFFF;
#pragma unroll
            for (int r = 0; r < KREG; ++r)
                if (better(lv[r], li[r], bv, bi_)) { bv = lv[r]; bi_ = li[r]; }
#pragma unroll
            for (int off = 1; off < 64; off <<= 1) {
                double ov = __shfl_xor(bv, off);
                int oi = __shfl_xor(bi_, off);
                if (better(ov, oi, bv, bi_)) { bv = ov; bi_ = oi; }
            }
            if (lane == round) { keep_v = bv; keep_i = bi_; }
#pragma unroll
            for (int r = 0; r < KREG; ++r)
                if (li[r] == bi_) { lv[r] = -DBL_MAX; li[r] = 0x7FFFFFFF; }
        }
        if (lane < NUM) { merge_val[wid * NUM + lane] = keep_v; merge_idx[wid * NUM + lane] = keep_i; }
        __syncthreads();

        if (wid == 0) {
            double c0 = merge_val[lane], c1 = merge_val[64 + lane];
            int i0_ = merge_idx[lane], i1_ = merge_idx[64 + lane];
            int cnt = 0;
            for (int round = 0; round < NUM; ++round) {
                double bv = c0;
                int bi_ = i0_;
                if (better(c1, i1_, bv, bi_)) { bv = c1; bi_ = i1_; }
#pragma unroll
                for (int off = 1; off < 64; off <<= 1) {
                    double ov = __shfl_xor(bv, off);
                    int oi = __shfl_xor(bi_, off);
                    if (better(ov, oi, bv, bi_)) { bv = ov; bi_ = oi; }
                }
                if (!(bv > 0.0)) break;
                if (lane == round) { topk_val[round] = bv; topk_idx[round] = bi_; }
                cnt++;
                if (i0_ == bi_) { c0 = -DBL_MAX; i0_ = 0x7FFFFFFF; }
                if (i1_ == bi_) { c1 = -DBL_MAX; i1_ = 0x7FFFFFFF; }
            }
            if (lane == 0) nsel = cnt;
        }
    }

    __syncthreads();
    const int S = nsel;
    if (tid < NUM && tid < S) sel_idx[tid] = topk_idx[tid];
    __syncthreads();
    if (tid == 0 && S < NUM) {
        int fill = S;
        for (int idx = 0; idx < HW && fill < NUM; ++idx) {
            int ii = idx >> 7, jj = idx & 127;
            double v = ws_at(xpl, ii, jj);
            bool zp = !(is_peak(xpl, ii, jj) && v != 0.0);
            if (zp) sel_idx[fill++] = idx;
        }
    }
    __syncthreads();

    if (tid < NUM) {
        const int idx = sel_idx[tid];
        const int h = idx >> 7, w = idx & 127;
        float* o0 = out + ((size_t)p * NUM + tid) * 9;
        for (int dr = 0; dr < 3; ++dr)
            for (int dc = 0; dc < 3; ++dc) {
                int rr = h - 1 + dr, cc = w - 1 + dc;
                float v = 0.f;
                if (rr >= 0 && rr < HH && cc >= 0 && cc < WW) v = xpl[rr * WW + cc];
                o0[dr * 3 + dc] = v;
            }
        float* o1 = out + (size_t)PLANES * NUM * 9 + ((size_t)p * NUM + tid) * 4;
        int x1 = max(w - 1, 0), y1 = max(h - 1, 0);
        int x2 = min(w + 1, WW - 1), y2 = min(h + 1, HH - 1);
        o1[0] = (float)x1;
        o1[1] = (float)y1;
        o1[2] = (float)x2;
        o1[3] = (float)y2;
    }
}

extern "C" void kernel_launch(void* const* d_in, const int* in_sizes, int n_in,
                              void* d_out, int out_size, void* d_ws, size_t ws_size,
                              hipStream_t stream) {
    const float* x = (const float*)d_in[0];
    float* out = (float*)d_out;
    (void)in_sizes; (void)n_in; (void)out_size;
    if (ws_size >= WS_NEED2) {
        int* counters = (int*)d_ws;
        unsigned long long* pool = (unsigned long long*)((char*)d_ws + (size_t)NCTR * 4);
        hipMemsetAsync(counters, 0, (size_t)NCTR * 4, stream);
        nms_stencil<<<PLANES * 4, NTHREADS, 0, stream>>>(x, counters, pool);
        nms_select<<<PLANES, NTHREADS, 0, stream>>>(x, counters, pool, out);
    } else {
        nms_kernel<<<PLANES, NTHREADS, 0, stream>>>(x, out);
    }
}

// Round 5
// 93.350 us; speedup vs baseline: 1.6515x; 1.6515x over previous
//
#include <hip/hip_runtime.h>
#include <cfloat>
#include <cstdint>

#define BB 8
#define CCH 64
#define HH 128
#define WW 128
#define HW (HH * WW)
#define NUM 32
#define PLANES (BB * CCH)
#define NTHREADS 256

// ---- split-path parameters ----
#define CAPP 3072                     // per-plane candidate cap (mean ~1820)
#define KREG2 12                      // CAPP / NTHREADS
#define NCTR 2048                     // counters region (ints), only PLANES used
#define WS_NEED2 ((size_t)NCTR * 4 + (size_t)PLANES * CAPP * 8)   // ~12.6 MB
#define PREFMASK 0xFFFFFFFFFFFFC000ull
#define POSKEY   0x8000000000000000ull
#define EIGHTHS 8
#define EROWS 16                      // rows per eighth
#define LBUF 640                      // LDS peak buffer entries (worst case ~576)

// ---- monolith fallback parameters ----
#define CAND_CAP 2176
#define KREG 9

// f64 window-sum at (i,j) with zero padding, fixed summation order.
__device__ double ws_at(const float* xpl, int i, int j) {
    double h[3];
    for (int d = -1; d <= 1; ++d) {
        int r = i + d;
        double a = 0.0, b = 0.0, c = 0.0;
        if (r >= 0 && r < HH) {
            const float* row = xpl + r * WW;
            a = (j - 1 >= 0) ? (double)row[j - 1] : 0.0;
            b = (double)row[j];
            c = (j + 1 < WW) ? (double)row[j + 1] : 0.0;
        }
        h[d + 1] = a + b + c;
    }
    return h[0] + h[1] + h[2];
}

__device__ bool is_peak(const float* xpl, int i, int j) {
    double v = ws_at(xpl, i, j);
    for (int di = -1; di <= 1; ++di)
        for (int dj = -1; dj <= 1; ++dj) {
            if (di == 0 && dj == 0) continue;
            int r = i + di, c = j + dj;
            if (r < 0 || r >= HH || c < 0 || c >= WW) continue;
            if (ws_at(xpl, r, c) > v) return false;
        }
    return true;
}

__device__ __forceinline__ bool better(double av, int ai, double bv, int bi) {
    return (av > bv) || (av == bv && ai < bi);
}

// order-preserving u64 of a double, then pack (value-prefix | 0x3FFF - idx)
__device__ __forceinline__ unsigned long long pack_key(double v, int idx) {
    unsigned long long u = (unsigned long long)__double_as_longlong(v);
    unsigned long long ord = u ^ (0x8000000000000000ull | (unsigned long long)((long long)u >> 63));
    return (ord & PREFMASK) | (unsigned long long)(0x3FFF - idx);
}

// ======================= Kernel 1: pure stencil (eighth-planes), peaks -> LDS -> global pool =======================
__global__ __launch_bounds__(NTHREADS) void nms_stencil(const float* __restrict__ x,
                                                        int* __restrict__ counters,
                                                        unsigned long long* __restrict__ pool) {
    const int blk = blockIdx.x;   // 4096 blocks
    const int p = blk >> 3;       // plane
    const int e = blk & 7;        // eighth
    const float* xpl = x + (size_t)p * HW;
    const int tid = threadIdx.x;
    unsigned long long* ppool = pool + (size_t)p * CAPP;
    int* pctr = counters + p;

    __shared__ float xs[20 * 128];              // 10240 B : rows e*16-2 .. e*16+17
    __shared__ unsigned long long lbuf[LBUF];   //  5120 B
    __shared__ int lcnt;
    __shared__ int gbase;

    if (tid == 0) lcnt = 0;

    const int base_row = e * EROWS - 2;
    for (int k = tid; k < 20 * 32; k += NTHREADS) {
        int rr = k >> 5, c4 = (k & 31) << 2;
        int gr = base_row + rr;
        float4 v = make_float4(0.f, 0.f, 0.f, 0.f);
        if (gr >= 0 && gr < HH) v = *(const float4*)(xpl + gr * WW + c4);
        *(float4*)(&xs[rr * 128 + c4]) = v;
    }
    __syncthreads();

    const int j = tid & 127;
    const int s = tid >> 7;
    const int i0 = e * EROWS + s * 8;   // 8 rows per thread

    auto HS3 = [&](int r, double h[3]) {
        const float* row = &xs[(r - base_row) * 128];
        double a = (j >= 2) ? (double)row[j - 2] : 0.0;
        double b = (j >= 1) ? (double)row[j - 1] : 0.0;
        double c = (double)row[j];
        double d = (j <= 126) ? (double)row[j + 1] : 0.0;
        double e2 = (j <= 125) ? (double)row[j + 2] : 0.0;
        h[0] = a + b + c;
        h[1] = b + c + d;
        h[2] = c + d + e2;
    };

    double hA[3], hB[3], hC[3];
    double wm[3], wc[3], wn[3];
    {
        double h0[3], h1[3];
        HS3(i0 - 2, h0);
        HS3(i0 - 1, h1);
        HS3(i0, hA);
        HS3(i0 + 1, hB);
        if (i0 - 1 >= 0) {
            wm[0] = h0[0] + h1[0] + hA[0];
            wm[1] = h0[1] + h1[1] + hA[1];
            wm[2] = h0[2] + h1[2] + hA[2];
        } else {
            wm[0] = wm[1] = wm[2] = -DBL_MAX;  // max-pool -inf pad
        }
        wc[0] = h1[0] + hA[0] + hB[0];
        wc[1] = h1[1] + hA[1] + hB[1];
        wc[2] = h1[2] + hA[2] + hB[2];
    }
    for (int i = i0; i < i0 + 8; ++i) {
        HS3(i + 2, hC);
        if (i + 1 < HH) {
            wn[0] = hA[0] + hB[0] + hC[0];
            wn[1] = hA[1] + hB[1] + hC[1];
            wn[2] = hA[2] + hB[2] + hC[2];
        } else {
            wn[0] = wn[1] = wn[2] = -DBL_MAX;
        }
        double v = wc[1];
        bool pk = (v >= wm[1]) && (v >= wn[1]);
        if (j > 0)   pk = pk && (v >= wm[0]) && (v >= wc[0]) && (v >= wn[0]);
        if (j < 127) pk = pk && (v >= wm[2]) && (v >= wc[2]) && (v >= wn[2]);

        if (pk) {
            int pos = atomicAdd(&lcnt, 1);
            unsigned long long key = pack_key(v, i * WW + j);
            if (pos < LBUF) lbuf[pos] = key;
            else {  // overflow (never expected): direct global append
                int slot = atomicAdd(pctr, 1);
                if (slot < CAPP) ppool[slot] = key;
            }
        }

        wm[0] = wc[0]; wm[1] = wc[1]; wm[2] = wc[2];
        wc[0] = wn[0]; wc[1] = wn[1]; wc[2] = wn[2];
        hA[0] = hB[0]; hA[1] = hB[1]; hA[2] = hB[2];
        hB[0] = hC[0]; hB[1] = hC[1]; hB[2] = hC[2];
    }
    __syncthreads();
    const int n = min(lcnt, LBUF);
    if (tid == 0) gbase = atomicAdd(pctr, n);
    __syncthreads();
    const int gb = gbase;
    for (int k = tid; k < n; k += NTHREADS) {
        int slot = gb + k;
        if (slot < CAPP) ppool[slot] = lbuf[k];
    }
}

// ======================= Kernel 2: per-plane top-32 on u64 keys + gather =======================
__global__ __launch_bounds__(NTHREADS) void nms_select(const float* __restrict__ x,
                                                       const int* __restrict__ counters,
                                                       const unsigned long long* __restrict__ pool,
                                                       float* __restrict__ out) {
    const int p = blockIdx.x;
    const int tid = threadIdx.x;
    const int lane = tid & 63;
    const int wid = tid >> 6;
    const float* xpl = x + (size_t)p * HW;
    const unsigned long long* pp = pool + (size_t)p * CAPP;

    __shared__ unsigned long long merge_key[4 * NUM];
    __shared__ int sel_idx[NUM];
    __shared__ int nsel_s;

    const int P = min(counters[p], CAPP);

    unsigned long long lk[KREG2];
#pragma unroll
    for (int r = 0; r < KREG2; ++r) {
        int ci = tid + (r << 8);
        lk[r] = (ci < P) ? pp[ci] : 0ull;
    }

    // per-wave top-32 (keys unique; 0 = sentinel)
    unsigned long long keep = 0ull;
    for (int round = 0; round < NUM; ++round) {
        unsigned long long b = 0ull;
#pragma unroll
        for (int r = 0; r < KREG2; ++r) b = (lk[r] > b) ? lk[r] : b;
#pragma unroll
        for (int off = 1; off < 64; off <<= 1) {
            unsigned long long o = __shfl_xor(b, off);
            b = (o > b) ? o : b;
        }
        if (lane == round) keep = b;
#pragma unroll
        for (int r = 0; r < KREG2; ++r)
            if (lk[r] == b) lk[r] = 0ull;
    }
    if (lane < NUM) merge_key[wid * NUM + lane] = keep;
    __syncthreads();

    // wave0: 128 -> 32 final merge, strictly-positive-value check
    if (wid == 0) {
        unsigned long long c0 = merge_key[lane], c1 = merge_key[64 + lane];
        int cnt = 0;
        for (int round = 0; round < NUM; ++round) {
            unsigned long long b = (c1 > c0) ? c1 : c0;
#pragma unroll
            for (int off = 1; off < 64; off <<= 1) {
                unsigned long long o = __shfl_xor(b, off);
                b = (o > b) ? o : b;
            }
            if (!((b & PREFMASK) > POSKEY)) break;  // only v>0 beats the zero pool
            if (lane == 0) sel_idx[round] = 0x3FFF - (int)(b & 0x3FFFull);
            cnt++;
            if (c0 == b) c0 = 0ull;
            if (c1 == b) c1 = 0ull;
        }
        if (lane == 0) nsel_s = cnt;
    }
    __syncthreads();
    const int S = nsel_s;
    // Degenerate fallback (<32 strictly-positive peaks) — never taken for this data.
    if (tid == 0 && S < NUM) {
        int fill = S;
        for (int idx = 0; idx < HW && fill < NUM; ++idx) {
            int ii = idx >> 7, jj = idx & 127;
            double v = ws_at(xpl, ii, jj);
            bool zp = !(is_peak(xpl, ii, jj) && v != 0.0);
            if (zp) sel_idx[fill++] = idx;
        }
    }
    __syncthreads();

    if (tid < NUM) {
        const int idx = sel_idx[tid];
        const int h = idx >> 7, w = idx & 127;
        float* o0 = out + ((size_t)p * NUM + tid) * 9;
        for (int dr = 0; dr < 3; ++dr)
            for (int dc = 0; dc < 3; ++dc) {
                int rr = h - 1 + dr, cc = w - 1 + dc;
                float v = 0.f;
                if (rr >= 0 && rr < HH && cc >= 0 && cc < WW) v = xpl[rr * WW + cc];
                o0[dr * 3 + dc] = v;
            }
        float* o1 = out + (size_t)PLANES * NUM * 9 + ((size_t)p * NUM + tid) * 4;
        int x1 = max(w - 1, 0), y1 = max(h - 1, 0);
        int x2 = min(w + 1, WW - 1), y2 = min(h + 1, HH - 1);
        o1[0] = (float)x1;
        o1[1] = (float)y1;
        o1[2] = (float)x2;
        o1[3] = (float)y2;
    }
}

// ======================= Fallback monolith (proven, R2) =======================
__global__ __launch_bounds__(NTHREADS) void nms_kernel(const float* __restrict__ x,
                                                       float* __restrict__ out) {
    const int p = blockIdx.x;
    const float* xpl = x + (size_t)p * HW;
    const int tid = threadIdx.x;
    const int lane = tid & 63;
    const int wid = tid >> 6;

    __shared__ float xs[68 * 128];
    __shared__ double cand_val[CAND_CAP];
    __shared__ int cand_idx[CAND_CAP];
    __shared__ int cand_cnt;
    __shared__ double merge_val[4 * NUM];
    __shared__ int merge_idx[4 * NUM];
    __shared__ double topk_val[NUM];
    __shared__ int topk_idx[NUM];
    __shared__ int nsel;
    __shared__ int sel_idx[NUM];

    if (tid == 0) nsel = 0;

    const int j = tid & 127;
    const int s = tid >> 7;

    for (int half = 0; half < 2; ++half) {
        const int base_row = half * 64 - 2;
        __syncthreads();
        if (tid == 0) cand_cnt = 0;
        for (int k = tid; k < 68 * 32; k += NTHREADS) {
            int rr = k >> 5, c4 = (k & 31) << 2;
            int gr = base_row + rr;
            float4 v = make_float4(0.f, 0.f, 0.f, 0.f);
            if (gr >= 0 && gr < HH) v = *(const float4*)(xpl + gr * WW + c4);
            *(float4*)(&xs[rr * 128 + c4]) = v;
        }
        __syncthreads();

        const int i0 = half * 64 + s * 32;

        auto HS3 = [&](int r, double h[3]) {
            const float* row = &xs[(r - base_row) * 128];
            double a = (j >= 2) ? (double)row[j - 2] : 0.0;
            double b = (j >= 1) ? (double)row[j - 1] : 0.0;
            double c = (double)row[j];
            double d = (j <= 126) ? (double)row[j + 1] : 0.0;
            double e = (j <= 125) ? (double)row[j + 2] : 0.0;
            h[0] = a + b + c;
            h[1] = b + c + d;
            h[2] = c + d + e;
        };

        double hA[3], hB[3], hC[3];
        double wm[3], wc[3], wn[3];
        {
            double h0[3], h1[3];
            HS3(i0 - 2, h0);
            HS3(i0 - 1, h1);
            HS3(i0, hA);
            HS3(i0 + 1, hB);
            if (i0 - 1 >= 0) {
                wm[0] = h0[0] + h1[0] + hA[0];
                wm[1] = h0[1] + h1[1] + hA[1];
                wm[2] = h0[2] + h1[2] + hA[2];
            } else {
                wm[0] = wm[1] = wm[2] = -DBL_MAX;
            }
            wc[0] = h1[0] + hA[0] + hB[0];
            wc[1] = h1[1] + hA[1] + hB[1];
            wc[2] = h1[2] + hA[2] + hB[2];
        }
        for (int i = i0; i < i0 + 32; ++i) {
            HS3(i + 2, hC);
            if (i + 1 < HH) {
                wn[0] = hA[0] + hB[0] + hC[0];
                wn[1] = hA[1] + hB[1] + hC[1];
                wn[2] = hA[2] + hB[2] + hC[2];
            } else {
                wn[0] = wn[1] = wn[2] = -DBL_MAX;
            }
            double v = wc[1];
            bool pk = (v >= wm[1]) && (v >= wn[1]);
            if (j > 0)   pk = pk && (v >= wm[0]) && (v >= wc[0]) && (v >= wn[0]);
            if (j < 127) pk = pk && (v >= wm[2]) && (v >= wc[2]) && (v >= wn[2]);
            if (pk) {
                int pos = atomicAdd(&cand_cnt, 1);
                if (pos < CAND_CAP) { cand_val[pos] = v; cand_idx[pos] = i * WW + j; }
            }
            wm[0] = wc[0]; wm[1] = wc[1]; wm[2] = wc[2];
            wc[0] = wn[0]; wc[1] = wn[1]; wc[2] = wn[2];
            hA[0] = hB[0]; hA[1] = hB[1]; hA[2] = hB[2];
            hB[0] = hC[0]; hB[1] = hC[1]; hB[2] = hC[2];
        }

        if (tid < nsel) {
            int pos = atomicAdd(&cand_cnt, 1);
            if (pos < CAND_CAP) { cand_val[pos] = topk_val[tid]; cand_idx[pos] = topk_idx[tid]; }
        }
        __syncthreads();
        const int P = min(cand_cnt, CAND_CAP);

        double lv[KREG];
        int li[KREG];
#pragma unroll
        for (int r = 0; r < KREG; ++r) {
            int ci = tid + (r << 8);
            if (ci < P) { lv[r] = cand_val[ci]; li[r] = cand_idx[ci]; }
            else        { lv[r] = -DBL_MAX;     li[r] = 0x7FFFFFFF; }
        }
        double keep_v = -DBL_MAX;
        int keep_i = 0x7FFFFFFF;
        for (int round = 0; round < NUM; ++round) {
            double bv = -DBL_MAX;
            int bi_ = 0x7FFFFFFF;
#pragma unroll
            for (int r = 0; r < KREG; ++r)
                if (better(lv[r], li[r], bv, bi_)) { bv = lv[r]; bi_ = li[r]; }
#pragma unroll
            for (int off = 1; off < 64; off <<= 1) {
                double ov = __shfl_xor(bv, off);
                int oi = __shfl_xor(bi_, off);
                if (better(ov, oi, bv, bi_)) { bv = ov; bi_ = oi; }
            }
            if (lane == round) { keep_v = bv; keep_i = bi_; }
#pragma unroll
            for (int r = 0; r < KREG; ++r)
                if (li[r] == bi_) { lv[r] = -DBL_MAX; li[r] = 0x7FFFFFFF; }
        }
        if (lane < NUM) { merge_val[wid * NUM + lane] = keep_v; merge_idx[wid * NUM + lane] = keep_i; }
        __syncthreads();

        if (wid == 0) {
            double c0 = merge_val[lane], c1 = merge_val[64 + lane];
            int i0_ = merge_idx[lane], i1_ = merge_idx[64 + lane];
            int cnt = 0;
            for (int round = 0; round < NUM; ++round) {
                double bv = c0;
                int bi_ = i0_;
                if (better(c1, i1_, bv, bi_)) { bv = c1; bi_ = i1_; }
#pragma unroll
                for (int off = 1; off < 64; off <<= 1) {
                    double ov = __shfl_xor(bv, off);
                    int oi = __shfl_xor(bi_, off);
                    if (better(ov, oi, bv, bi_)) { bv = ov; bi_ = oi; }
                }
                if (!(bv > 0.0)) break;
                if (lane == round) { topk_val[round] = bv; topk_idx[round] = bi_; }
                cnt++;
                if (i0_ == bi_) { c0 = -DBL_MAX; i0_ = 0x7FFFFFFF; }
                if (i1_ == bi_) { c1 = -DBL_MAX; i1_ = 0x7FFFFFFF; }
            }
            if (lane == 0) nsel = cnt;
        }
    }

    __syncthreads();
    const int S = nsel;
    if (tid < NUM && tid < S) sel_idx[tid] = topk_idx[tid];
    __syncthreads();
    if (tid == 0 && S < NUM) {
        int fill = S;
        for (int idx = 0; idx < HW && fill < NUM; ++idx) {
            int ii = idx >> 7, jj = idx & 127;
            double v = ws_at(xpl, ii, jj);
            bool zp = !(is_peak(xpl, ii, jj) && v != 0.0);
            if (zp) sel_idx[fill++] = idx;
        }
    }
    __syncthreads();

    if (tid < NUM) {
        const int idx = sel_idx[tid];
        const int h = idx >> 7, w = idx & 127;
        float* o0 = out + ((size_t)p * NUM + tid) * 9;
        for (int dr = 0; dr < 3; ++dr)
            for (int dc = 0; dc < 3; ++dc) {
                int rr = h - 1 + dr, cc = w - 1 + dc;
                float v = 0.f;
                if (rr >= 0 && rr < HH && cc >= 0 && cc < WW) v = xpl[rr * WW + cc];
                o0[dr * 3 + dc] = v;
            }
        float* o1 = out + (size_t)PLANES * NUM * 9 + ((size_t)p * NUM + tid) * 4;
        int x1 = max(w - 1, 0), y1 = max(h - 1, 0);
        int x2 = min(w + 1, WW - 1), y2 = min(h + 1, HH - 1);
        o1[0] = (float)x1;
        o1[1] = (float)y1;
        o1[2] = (float)x2;
        o1[3] = (float)y2;
    }
}

extern "C" void kernel_launch(void* const* d_in, const int* in_sizes, int n_in,
                              void* d_out, int out_size, void* d_ws, size_t ws_size,
                              hipStream_t stream) {
    const float* x = (const float*)d_in[0];
    float* out = (float*)d_out;
    (void)in_sizes; (void)n_in; (void)out_size;
    if (ws_size >= WS_NEED2) {
        int* counters = (int*)d_ws;
        unsigned long long* pool = (unsigned long long*)((char*)d_ws + (size_t)NCTR * 4);
        hipMemsetAsync(counters, 0, (size_t)NCTR * 4, stream);
        nms_stencil<<<PLANES * EIGHTHS, NTHREADS, 0, stream>>>(x, counters, pool);
        nms_select<<<PLANES, NTHREADS, 0, stream>>>(x, counters, pool, out);
    } else {
        nms_kernel<<<PLANES, NTHREADS, 0, stream>>>(x, out);
    }
}